// Round 2
// baseline (541.757 us; speedup 1.0000x reference)
//
#include <hip/hip_runtime.h>
#include <stdint.h>

// Problem constants (from reference)
#define NB   8
#define AB   256
#define HB   128
#define WB   128
#define CB   19
#define CP1  20
#define PLANE (HB*WB)          // 16384
#define NPIX  (NB*PLANE)       // 131072

// ---------------------------------------------------------------------------
// Kernel A: nearest-neighbor label downsample -> u8 labels, plus class counts
// ---------------------------------------------------------------------------
__global__ __launch_bounds__(256) void k_labels(const int* __restrict__ target,
                                                unsigned char* __restrict__ labels,
                                                float* __restrict__ counts) {
    __shared__ int hist[CP1];
    int tid = threadIdx.x;
    if (tid < CP1) hist[tid] = 0;
    __syncthreads();

    int p = blockIdx.x * 256 + tid;          // p in [0, NPIX)
    int n   = p >> 14;                       // /16384
    int rem = p & 16383;
    int h   = rem >> 7;
    int w   = rem & 127;
    // src idx: target[n, h*8, w*8], target is [N,1024,1024]
    size_t idx = (size_t)n * 1048576 + (size_t)h * 8192 + (size_t)w * 8;
    int l = target[idx];
    labels[p] = (unsigned char)l;
    int lab0 = (l == 255) ? 0 : l;
    if (lab0 < 0 || lab0 >= CP1) lab0 = 0;   // safety clamp
    atomicAdd(&hist[lab0], 1);
    __syncthreads();
    if (tid < CP1) atomicAdd(&counts[tid], (float)hist[tid]);
}

// ---------------------------------------------------------------------------
// Kernel B (v2): per-class, per-channel sum / sum-of-squares over features.
// One block per (n, a, half-plane). Per-wave global_load_lds triple-buffer
// staging (counted vmcnt, no loop barriers), fire-and-forget ds_add_f32
// accumulation into a bank-conflict-free acc[class][stat][128] layout.
// LDS: 20 KB acc + 12 KB stage = 32 KB -> 5 blocks/CU (20 waves/CU).
// ---------------------------------------------------------------------------
__global__ __launch_bounds__(256) void k_stats(const float* __restrict__ features,
                                               const unsigned char* __restrict__ labels,
                                               float* __restrict__ gsum,
                                               float* __restrict__ gsq) {
    __shared__ float acc[CP1 * 2 * 128];     // [class][stat][col], 20480 B
    __shared__ float fbuf[3][4][256];        // [buf][wave][1 KB], 12288 B

    const int tid  = threadIdx.x;
    const int lane = tid & 63;
    const int w    = tid >> 6;
    const int col  = tid & 127;

    for (int i = tid; i < CP1 * 2 * 128; i += 256) acc[i] = 0.f;

    const int b    = blockIdx.x;             // [0, 4096)
    const int half = b & 1;
    const int a    = (b >> 1) & 255;
    const int n    = b >> 9;

    const float* fsrc = features + ((size_t)(n * AB + a)) * PLANE
                        + half * 8192 + w * 2048 + lane * 4;
    const uint32_t* lsrc = (const uint32_t*)(labels + (size_t)n * PLANE + half * 8192)
                           + w * 512 + lane;

    // preload this thread's 32 labels (8 words)
    uint32_t lw[8];
    #pragma unroll
    for (int it = 0; it < 8; ++it) lw[it] = lsrc[it * 64];

    __syncthreads();                         // acc zero-init visible to all waves

    #define STAGE(IT, BUF)                                                        \
        __builtin_amdgcn_global_load_lds(                                         \
            (const __attribute__((address_space(1))) void*)(fsrc + (IT) * 256),   \
            (__attribute__((address_space(3))) void*)(&fbuf[BUF][w][lane * 4]),   \
            16, 0, 0)

    STAGE(0, 0);
    STAGE(1, 1);

    #pragma unroll
    for (int it = 0; it < 8; ++it) {
        if (it + 2 < 8) STAGE(it + 2, (it + 2) % 3);
        // wait for stage(it); stages it+1/it+2 stay in flight (per-wave vmcnt)
        if (it < 6)      asm volatile("s_waitcnt vmcnt(2)" ::: "memory");
        else if (it == 6) asm volatile("s_waitcnt vmcnt(1)" ::: "memory");
        else              asm volatile("s_waitcnt vmcnt(0)" ::: "memory");

        float4 f = *(const float4*)&fbuf[it % 3][w][lane * 4];
        uint32_t lwv = lw[it];
        float fa[4] = {f.x, f.y, f.z, f.w};
        #pragma unroll
        for (int j = 0; j < 4; ++j) {
            int l = (lwv >> (8 * j)) & 255;
            l = (l >= CP1) ? 0 : l;          // 255 (and any oob) -> 0
            float v = fa[j];
            atomicAdd(&acc[l * 256 + col], v);           // ds_add_f32, no chain
            atomicAdd(&acc[l * 256 + 128 + col], v * v);
        }
    }
    #undef STAGE

    __syncthreads();                         // drain all waves' ds_add

    // tree-reduce 128 columns for all 40 (class,stat) rows
    #pragma unroll
    for (int off = 64; off >= 1; off >>= 1) {
        for (int i = tid; i < CP1 * 2 * off; i += 256) {
            int cs = i / off;
            int j  = i - cs * off;
            acc[cs * 128 + j] += acc[cs * 128 + j + off];
        }
        __syncthreads();
    }

    if (tid < CP1 * 2) {
        float v = acc[tid * 128];
        int l = tid >> 1, s = tid & 1;
        float* dst = s ? gsq : gsum;
        atomicAdd(&dst[l * 256 + a], v);
    }
}

// ---------------------------------------------------------------------------
// Kernel C: ave/var/new_cov -> sigma2 lookup table [CP1][CB].
// One block per label l; after setup each wave handles c = wave, wave+4, ...
// (no barriers in the c-loop).
// ---------------------------------------------------------------------------
__global__ __launch_bounds__(256) void k_table(const float* __restrict__ counts,
                                               const float* __restrict__ gsum,
                                               const float* __restrict__ gsq,
                                               const float* __restrict__ fcw,
                                               const float* __restrict__ Ave,
                                               const float* __restrict__ CoV,
                                               const float* __restrict__ Amount,
                                               const int* __restrict__ ratio_p,
                                               float* __restrict__ table) {
    __shared__ float ncov_s[256];
    __shared__ float wl_s[256];
    int t = threadIdx.x;
    int l = blockIdx.x;

    float cnt  = counts[l];
    float cntc = (cnt == 0.f) ? 1.f : cnt;
    float sum  = gsum[l * 256 + t];
    float sq   = gsq [l * 256 + t];
    float ave  = sum / cntc;
    float var  = sq / cntc - ave * ave;
    float denom = cnt + Amount[l];
    float wcv  = (denom > 0.f) ? cnt / denom : 0.f;
    float d0   = Ave[l * 256 + t] - ave;
    float ncov = CoV[l * 256 + t] * (1.f - wcv) + var * wcv + wcv * (1.f - wcv) * d0 * d0;

    ncov_s[t] = ncov;
    int lwr = (l < CB) ? l : (CB - 1);       // row 19 never used (counts[19]==0)
    wl_s[t] = fcw[lwr * 256 + t];
    __syncthreads();

    int wv = t >> 6, lane = t & 63;
    float ratio_f = (float)(*ratio_p);
    for (int c = wv; c < CB; c += 4) {
        float4 nc = *(const float4*)&ncov_s[lane * 4];
        float4 wl = *(const float4*)&wl_s[lane * 4];
        float4 wc = *(const float4*)&fcw[c * 256 + lane * 4];
        float e0 = wc.x - wl.x, e1 = wc.y - wl.y, e2 = wc.z - wl.z, e3 = wc.w - wl.w;
        float r = nc.x * e0 * e0 + nc.y * e1 * e1 + nc.z * e2 * e2 + nc.w * e3 * e3;
        #pragma unroll
        for (int off = 32; off; off >>= 1) r += __shfl_down(r, off);
        if (lane == 0) table[l * CB + c] = ratio_f * r;
    }
}

// ---------------------------------------------------------------------------
// Kernel D: out[n,c,h,w] = y[n,c,h,w] + 0.5 * table[lab[n,h,w]][c] * keep
// ---------------------------------------------------------------------------
__global__ __launch_bounds__(256) void k_apply(const float* __restrict__ y,
                                               const unsigned char* __restrict__ labels,
                                               const float* __restrict__ table,
                                               float* __restrict__ out) {
    __shared__ float tab[CP1 * CB];
    int tid = threadIdx.x;
    for (int i = tid; i < CP1 * CB; i += 256) tab[i] = table[i];
    __syncthreads();

    int b = blockIdx.x;
    int chunk = b & 3;
    int c = (b >> 2) % CB;
    int n = b / (4 * CB);

    const float* ybase = y + ((size_t)(n * CB + c)) * PLANE;
    float* obase = out + ((size_t)(n * CB + c)) * PLANE;
    const unsigned char* lbase = labels + (size_t)n * PLANE;

    #pragma unroll
    for (int it = 0; it < 4; ++it) {
        int pix = chunk * 4096 + it * 1024 + tid * 4;
        float4 yv = *reinterpret_cast<const float4*>(ybase + pix);
        unsigned int lwv = *reinterpret_cast<const unsigned int*>(lbase + pix);
        float ya[4] = {yv.x, yv.y, yv.z, yv.w};
        float o[4];
        #pragma unroll
        for (int j = 0; j < 4; ++j) {
            int l = (lwv >> (8 * j)) & 255;
            bool keep = (l != 255);
            int lab0 = keep ? (l < CP1 ? l : 0) : 0;
            float s = tab[lab0 * CB + c];
            o[j] = ya[j] + (keep ? 0.5f * s : 0.f);
        }
        *reinterpret_cast<float4*>(obase + pix) = make_float4(o[0], o[1], o[2], o[3]);
    }
}

// ---------------------------------------------------------------------------
extern "C" void kernel_launch(void* const* d_in, const int* in_sizes, int n_in,
                              void* d_out, int out_size, void* d_ws, size_t ws_size,
                              hipStream_t stream) {
    const float* features = (const float*)d_in[0];   // [8,256,128,128]
    const float* y        = (const float*)d_in[1];   // [8,19,128,128]
    const float* fcw      = (const float*)d_in[2];   // [19,256]
    const float* Ave      = (const float*)d_in[3];   // [20,256]
    const float* CoV      = (const float*)d_in[4];   // [20,256]
    const float* Amount   = (const float*)d_in[5];   // [20]
    const int*   target   = (const int*)d_in[6];     // [8,1024,1024]
    const int*   ratio    = (const int*)d_in[7];     // scalar

    char* ws = (char*)d_ws;
    float* counts = (float*)(ws + 0);                // 20 f32 (pad to 128 B)
    float* gsum   = (float*)(ws + 128);              // 20*256 f32
    float* gsq    = (float*)(ws + 20608);            // 20*256 f32
    unsigned char* labels = (unsigned char*)(ws + 41088);   // 131072 u8
    float* table  = (float*)(ws + 41088 + 131072);   // 20*19 f32
    float* out    = (float*)d_out;

    // zero the accumulators (ws is poisoned 0xAA before each launch)
    hipMemsetAsync(ws, 0, 41088, stream);

    k_labels<<<NPIX / 256,  256, 0, stream>>>(target, labels, counts);
    k_stats <<<NB * AB * 2, 256, 0, stream>>>(features, labels, gsum, gsq);
    k_table <<<CP1,         256, 0, stream>>>(counts, gsum, gsq, fcw, Ave, CoV, Amount, ratio, table);
    k_apply <<<NB * CB * 4, 256, 0, stream>>>(y, labels, table, out);
}

// Round 3
// 243.892 us; speedup vs baseline: 2.2213x; 2.2213x over previous
//
#include <hip/hip_runtime.h>
#include <stdint.h>

// Problem constants (from reference)
#define NB   8
#define AB   256
#define HB   128
#define WB   128
#define CB   19
#define CP1  20
#define PLANE (HB*WB)          // 16384
#define NPIX  (NB*PLANE)       // 131072
#define NREP 8                 // replicated global accumulators (atomic contention /8)

typedef __attribute__((ext_vector_type(8))) short bf8_t;
typedef __attribute__((ext_vector_type(4))) float f4_t;
union ABu { bf8_t v; unsigned short u[8]; };

__device__ inline unsigned short f2bf(float f) {      // RNE fp32->bf16 (finite inputs)
    unsigned int u = __float_as_uint(f);
    return (unsigned short)((u + 0x7FFFu + ((u >> 16) & 1u)) >> 16);
}

// ---------------------------------------------------------------------------
// Kernel A: nearest-neighbor label downsample -> raw u8 + mapped u8, + counts
// ---------------------------------------------------------------------------
__global__ __launch_bounds__(256) void k_labels(const int* __restrict__ target,
                                                unsigned char* __restrict__ labels,
                                                unsigned char* __restrict__ lab0,
                                                float* __restrict__ counts) {
    __shared__ int hist[CP1];
    int tid = threadIdx.x;
    if (tid < CP1) hist[tid] = 0;
    __syncthreads();

    int p = blockIdx.x * 256 + tid;          // p in [0, NPIX)
    int n   = p >> 14;
    int rem = p & 16383;
    int h   = rem >> 7;
    int w   = rem & 127;
    size_t idx = (size_t)n * 1048576 + (size_t)h * 8192 + (size_t)w * 8;
    int l = target[idx];
    labels[p] = (unsigned char)l;
    int m = (l == 255) ? 0 : ((l >= 0 && l < CP1) ? l : 0);
    lab0[p] = (unsigned char)m;
    atomicAdd(&hist[m], 1);
    __syncthreads();
    if (tid < CP1) atomicAdd(&counts[tid], (float)hist[tid]);
}

// ---------------------------------------------------------------------------
// Kernel B (v3): per-class sum/sumsq via MFMA.
// S[l,a] = onehot[l,p] . F[a,p] ; one-hot built in-register from labels.
// Block = 4 waves; wave owns 16 channels, block owns 64 ch x 512 px.
// Grid = 8n x 32pc x 4cg = 1024. No LDS accumulation, no loop barriers.
// ---------------------------------------------------------------------------
__global__ __launch_bounds__(256) void k_stats(const float* __restrict__ features,
                                               const unsigned char* __restrict__ lab0,
                                               float* __restrict__ gsumR,
                                               float* __restrict__ gsqR) {
    __shared__ uint2 labs[64];               // 512 labels
    const int tid  = threadIdx.x;
    const int lane = tid & 63;
    const int w    = tid >> 6;

    const int bx = blockIdx.x;
    const int cg = bx & 3;                   // channel group (64 ch)
    const int pc = (bx >> 2) & 31;           // pixel chunk (512 px)
    const int n  = bx >> 7;
    const int rep = bx & (NREP - 1);

    if (tid < 64)
        labs[tid] = ((const uint2*)(lab0 + (size_t)n * PLANE + pc * 512))[tid];
    __syncthreads();

    const int col = lane & 15;               // channel-within-tile, == B col, == D col
    const int pg  = (lane >> 4) * 8;         // k sub-offset within 32-pixel step
    const int ch  = cg * 64 + w * 16 + col;
    const float* fbase = features + ((size_t)(n * AB + ch)) * PLANE + pc * 512 + pg;

    f4_t aS0 = {0.f,0.f,0.f,0.f}, aQ0 = {0.f,0.f,0.f,0.f};   // classes 0-15
    f4_t aS1 = {0.f,0.f,0.f,0.f}, aQ1 = {0.f,0.f,0.f,0.f};   // classes 16-19

    const unsigned int t0 = (unsigned int)col;
    const unsigned int t1 = 16u + (unsigned int)col;

    #pragma unroll 4
    for (int t = 0; t < 16; ++t) {
        float4 va = *(const float4*)(fbase + t * 32);
        float4 vb = *(const float4*)(fbase + t * 32 + 4);
        uint2 lw = labs[(t * 32 + pg) >> 3];
        unsigned int bb[8] = { lw.x & 255u, (lw.x >> 8) & 255u, (lw.x >> 16) & 255u, lw.x >> 24,
                               lw.y & 255u, (lw.y >> 8) & 255u, (lw.y >> 16) & 255u, lw.y >> 24 };
        float fv[8] = { va.x, va.y, va.z, va.w, vb.x, vb.y, vb.z, vb.w };
        ABu a0, a1, bs, bq;
        #pragma unroll
        for (int j = 0; j < 8; ++j) {
            a0.u[j] = (bb[j] == t0) ? (unsigned short)0x3F80 : (unsigned short)0;
            a1.u[j] = (bb[j] == t1) ? (unsigned short)0x3F80 : (unsigned short)0;
            bs.u[j] = f2bf(fv[j]);
            bq.u[j] = f2bf(fv[j] * fv[j]);
        }
        aS0 = __builtin_amdgcn_mfma_f32_16x16x32_bf16(a0.v, bs.v, aS0, 0, 0, 0);
        aS1 = __builtin_amdgcn_mfma_f32_16x16x32_bf16(a1.v, bs.v, aS1, 0, 0, 0);
        aQ0 = __builtin_amdgcn_mfma_f32_16x16x32_bf16(a0.v, bq.v, aQ0, 0, 0, 0);
        aQ1 = __builtin_amdgcn_mfma_f32_16x16x32_bf16(a1.v, bq.v, aQ1, 0, 0, 0);
    }

    // D layout (m89): col = lane&15 (channel), row = (lane>>4)*4 + reg (class)
    float* gs = gsumR + rep * (CP1 * 256);
    float* gq = gsqR  + rep * (CP1 * 256);
    const int rbase = (lane >> 4) * 4;
    #pragma unroll
    for (int r = 0; r < 4; ++r) {
        atomicAdd(&gs[(rbase + r) * 256 + ch], aS0[r]);
        atomicAdd(&gq[(rbase + r) * 256 + ch], aQ0[r]);
    }
    if (rbase == 0) {                        // rows 0-3 of tile2 = classes 16-19
        #pragma unroll
        for (int r = 0; r < 4; ++r) {
            atomicAdd(&gs[(16 + r) * 256 + ch], aS1[r]);
            atomicAdd(&gq[(16 + r) * 256 + ch], aQ1[r]);
        }
    }
}

// ---------------------------------------------------------------------------
// Kernel C: reduce replicas, ave/var/new_cov -> sigma2 table [CP1][CB]
// ---------------------------------------------------------------------------
__global__ __launch_bounds__(256) void k_table(const float* __restrict__ counts,
                                               const float* __restrict__ gsumR,
                                               const float* __restrict__ gsqR,
                                               const float* __restrict__ fcw,
                                               const float* __restrict__ Ave,
                                               const float* __restrict__ CoV,
                                               const float* __restrict__ Amount,
                                               const int* __restrict__ ratio_p,
                                               float* __restrict__ table) {
    __shared__ float ncov_s[256];
    __shared__ float wl_s[256];
    int t = threadIdx.x;
    int l = blockIdx.x;

    float sum = 0.f, sq = 0.f;
    #pragma unroll
    for (int r = 0; r < NREP; ++r) {
        sum += gsumR[r * (CP1 * 256) + l * 256 + t];
        sq  += gsqR [r * (CP1 * 256) + l * 256 + t];
    }

    float cnt  = counts[l];
    float cntc = (cnt == 0.f) ? 1.f : cnt;
    float ave  = sum / cntc;
    float var  = sq / cntc - ave * ave;
    float denom = cnt + Amount[l];
    float wcv  = (denom > 0.f) ? cnt / denom : 0.f;
    float d0   = Ave[l * 256 + t] - ave;
    float ncov = CoV[l * 256 + t] * (1.f - wcv) + var * wcv + wcv * (1.f - wcv) * d0 * d0;

    ncov_s[t] = ncov;
    int lwr = (l < CB) ? l : (CB - 1);       // row 19 never used (counts[19]==0)
    wl_s[t] = fcw[lwr * 256 + t];
    __syncthreads();

    int wv = t >> 6, lane = t & 63;
    float ratio_f = (float)(*ratio_p);
    for (int c = wv; c < CB; c += 4) {
        float4 nc = *(const float4*)&ncov_s[lane * 4];
        float4 wl = *(const float4*)&wl_s[lane * 4];
        float4 wc = *(const float4*)&fcw[c * 256 + lane * 4];
        float e0 = wc.x - wl.x, e1 = wc.y - wl.y, e2 = wc.z - wl.z, e3 = wc.w - wl.w;
        float r = nc.x * e0 * e0 + nc.y * e1 * e1 + nc.z * e2 * e2 + nc.w * e3 * e3;
        #pragma unroll
        for (int off = 32; off; off >>= 1) r += __shfl_down(r, off);
        if (lane == 0) table[l * CB + c] = ratio_f * r;
    }
}

// ---------------------------------------------------------------------------
// Kernel D: out[n,c,h,w] = y[n,c,h,w] + 0.5 * table[lab[n,h,w]][c] * keep
// ---------------------------------------------------------------------------
__global__ __launch_bounds__(256) void k_apply(const float* __restrict__ y,
                                               const unsigned char* __restrict__ labels,
                                               const float* __restrict__ table,
                                               float* __restrict__ out) {
    __shared__ float tab[CP1 * CB];
    int tid = threadIdx.x;
    for (int i = tid; i < CP1 * CB; i += 256) tab[i] = table[i];
    __syncthreads();

    int b = blockIdx.x;
    int chunk = b & 3;
    int c = (b >> 2) % CB;
    int n = b / (4 * CB);

    const float* ybase = y + ((size_t)(n * CB + c)) * PLANE;
    float* obase = out + ((size_t)(n * CB + c)) * PLANE;
    const unsigned char* lbase = labels + (size_t)n * PLANE;

    #pragma unroll
    for (int it = 0; it < 4; ++it) {
        int pix = chunk * 4096 + it * 1024 + tid * 4;
        float4 yv = *reinterpret_cast<const float4*>(ybase + pix);
        unsigned int lwv = *reinterpret_cast<const unsigned int*>(lbase + pix);
        float ya[4] = {yv.x, yv.y, yv.z, yv.w};
        float o[4];
        #pragma unroll
        for (int j = 0; j < 4; ++j) {
            int l = (lwv >> (8 * j)) & 255;
            bool keep = (l != 255);
            int lab0i = keep ? (l < CP1 ? l : 0) : 0;
            float s = tab[lab0i * CB + c];
            o[j] = ya[j] + (keep ? 0.5f * s : 0.f);
        }
        *reinterpret_cast<float4*>(obase + pix) = make_float4(o[0], o[1], o[2], o[3]);
    }
}

// ---------------------------------------------------------------------------
extern "C" void kernel_launch(void* const* d_in, const int* in_sizes, int n_in,
                              void* d_out, int out_size, void* d_ws, size_t ws_size,
                              hipStream_t stream) {
    const float* features = (const float*)d_in[0];   // [8,256,128,128]
    const float* y        = (const float*)d_in[1];   // [8,19,128,128]
    const float* fcw      = (const float*)d_in[2];   // [19,256]
    const float* Ave      = (const float*)d_in[3];   // [20,256]
    const float* CoV      = (const float*)d_in[4];   // [20,256]
    const float* Amount   = (const float*)d_in[5];   // [20]
    const int*   target   = (const int*)d_in[6];     // [8,1024,1024]
    const int*   ratio    = (const int*)d_in[7];     // scalar

    char* ws = (char*)d_ws;
    float* counts = (float*)(ws + 0);                       // 20 f32 (pad 128 B)
    float* gsumR  = (float*)(ws + 128);                     // 8*20*256 f32 = 163840 B
    float* gsqR   = (float*)(ws + 128 + 163840);            // 8*20*256 f32
    unsigned char* labels = (unsigned char*)(ws + 327808);  // 131072 u8 (raw)
    unsigned char* lab0   = (unsigned char*)(ws + 458880);  // 131072 u8 (mapped)
    float* table  = (float*)(ws + 589952);                  // 20*19 f32
    float* out    = (float*)d_out;

    // zero counts + replicated accumulators
    hipMemsetAsync(ws, 0, 327808, stream);

    k_labels<<<NPIX / 256,   256, 0, stream>>>(target, labels, lab0, counts);
    k_stats <<<NB * 32 * 4,  256, 0, stream>>>(features, lab0, gsumR, gsqR);
    k_table <<<CP1,          256, 0, stream>>>(counts, gsumR, gsqR, fcw, Ave, CoV, Amount, ratio, table);
    k_apply <<<NB * CB * 4,  256, 0, stream>>>(y, labels, table, out);
}